// Round 1
// 78.477 us; speedup vs baseline: 1.0258x; 1.0258x over previous
//
#include <hip/hip_runtime.h>

// B=64, L=256, C_IN=5, KERNEL=4, C=8. 253 steps padded to 256 = 8 chunks x 32.
// ONE kernel, 256 blocks = (batch 64) x (i-pair 4), 512 thr = 8 waves.
// wave = chunk (32 serial iters), 1 block/CU, 2 waves/SIMD device-wide.
//
// R11 (this round): channel-permutation dedup + single-barrier s4 reduce.
//  * Per-block self-inverse channel permutation pi(c)=c^i0 on {0,1,i0,i1}
//    (identity elsewhere), applied when staging dxs in LDS. The block's two
//    level-4 rows land in permuted slots 0,1 => the u1/u2/u3 state (which was
//    provably identical to t1/t2r/t3r[i0+m], same recurrences/inputs) is
//    deleted, along with the 6 cndmask/step a0/a1 selects and all runtime
//    lp[i0+m] table indexing. c4_m now reads t-state (pre-update) at
//    compile-time indices 0/1. Un-permute only at the final global writes
//    (pi maps even pairs to even pairs, so float2 s4 stores stay vectorized).
//  * Phase 4: 8 serialized barrier rounds -> each wave writes s4v to a 32KB
//    LDS array (replaces pad_lds; LDS total 58.8KB keeps the <=2 blocks/CU
//    cap), one barrier, every thread sums its float2 across the 8 waves in
//    ascending w (same summation order as before => bit-identical output).
// Hard constraints from R9/R10: per-thread state needs >=128 VGPRs
// (block <= 512 thr); no N-way inlined specialization of the scan; no ds_add.
#define L_IN  256
#define CIN   5
#define SIG_N 4680   // 8 + 64 + 512 + 4096

__global__ __launch_bounds__(512) void sig_fused_kernel(
    const float* __restrict__ inp,
    const float* __restrict__ w1, const float* __restrict__ b1,
    const float* __restrict__ w2, const float* __restrict__ b2,
    const float* __restrict__ w3, const float* __restrict__ b3,
    float* __restrict__ out)
{
    const int blk  = blockIdx.x;      // 0..255
    const int b    = blk >> 2;        // batch
    const int iq   = blk & 3;         // i0=2iq, i1=2iq+1
    const int i0   = 2 * iq;
    const int tid  = threadIdx.x;     // 0..511
    const int w    = tid >> 6;        // wave 0..7 = chunk id
    const int lane = tid & 63;
    const int j    = lane >> 3;
    const int k    = lane & 7;

    __shared__ __align__(16) float dxs[264][8];    // 256 steps + zero slop (PERMUTED channels)
    __shared__ __align__(16) float sig3[8][592];   // per-chunk s1|s2|s3 (584 used, permuted)
    __shared__ __align__(16) float s4red[8][1024]; // per-wave s4 partials (32KB; also LDS occupancy cap)

    // self-inverse per-block channel permutation (identity when iq==0)
    auto PI = [&](int x) {
        return (((x >> 1) == 0) | ((x >> 1) == iq)) ? (x ^ i0) : x;
    };

    // ---------------- phase 1: conv augment -> increments ----------------
    const float* __restrict__ x = inp + b * (L_IN * CIN);
    float o[8];
    if (tid < 253) {
        float h1[8];
        #pragma unroll
        for (int q = 0; q < 8; ++q) h1[q] = b1[q];
        #pragma unroll
        for (int kk = 0; kk < 4; ++kk) {
            #pragma unroll
            for (int ci = 0; ci < CIN; ++ci) {
                float v = x[(tid + kk) * CIN + ci];
                #pragma unroll
                for (int q = 0; q < 8; ++q) h1[q] = fmaf(v, w1[q * 20 + ci * 4 + kk], h1[q]);
            }
        }
        float r1v[8];
        #pragma unroll
        for (int q = 0; q < 8; ++q) r1v[q] = h1[q] > 0.f ? h1[q] : 0.f;
        float h2[8];
        #pragma unroll
        for (int q = 0; q < 8; ++q) h2[q] = b2[q];
        #pragma unroll
        for (int p = 0; p < 8; ++p) {
            #pragma unroll
            for (int q = 0; q < 8; ++q) h2[q] = fmaf(r1v[p], w2[q * 8 + p], h2[q]);
        }
        float r2v[8];
        #pragma unroll
        for (int q = 0; q < 8; ++q) r2v[q] = h2[q] > 0.f ? h2[q] : 0.f;
        float h30 = b3[0], h31 = b3[1];
        #pragma unroll
        for (int p = 0; p < 8; ++p) {
            h30 = fmaf(r2v[p], w3[p], h30);
            h31 = fmaf(r2v[p], w3[8 + p], h31);
        }
        #pragma unroll
        for (int cc = 0; cc < 5; ++cc) o[cc] = x[(tid + 3) * CIN + cc];
        o[5] = (float)(tid + 3) * (1.0f / 255.0f);
        o[6] = h30;
        o[7] = h31;
    }
    if (tid < 88) dxs[253 + (tid >> 3)][tid & 7] = 0.f;   // zero rows 253..263
    if (tid < 253) {
        #pragma unroll
        for (int c = 0; c < 8; ++c) dxs[tid][PI(c)] = o[c];   // permuted path rows
    }
    __syncthreads();
    float curr[8], prevr[8];
    if (tid < 253) {
        #pragma unroll
        for (int ch = 0; ch < 8; ++ch) {
            curr[ch]  = dxs[tid][ch];
            prevr[ch] = (tid > 0) ? dxs[tid - 1][ch] : 0.f;
        }
    }
    __syncthreads();
    if (tid < 253) {
        #pragma unroll
        for (int ch = 0; ch < 8; ++ch) dxs[tid][ch] = curr[ch] - prevr[ch];
    }
    __syncthreads();

    // ---------------- phase 2: one 32-step chunk per wave ----------------
    // All channel indices below are PERMUTED; slots 0,1 are the block's i-pair.
    const int rbase = w * 32;
    float t1[8], t2r[8], t3r[8];          // full level1-3 (all 8 channels) for table
    float s4v[2][8];
    #pragma unroll
    for (int i = 0; i < 8; ++i) { t1[i] = 0.f; t2r[i] = 0.f; t3r[i] = 0.f; }
    #pragma unroll
    for (int m = 0; m < 2; ++m)
        #pragma unroll
        for (int l = 0; l < 8; ++l) s4v[m][l] = 0.f;

    const float4* __restrict__ dx4 = reinterpret_cast<const float4*>(&dxs[0][0]);
    float own_p[2], bb_p[2];
    float4 r0_p[2], r1_p[2];
    #pragma unroll
    for (int u = 0; u < 2; ++u) {
        own_p[u] = dxs[rbase + u][k];
        bb_p[u]  = dxs[rbase + u][j];
        r0_p[u]  = dx4[2 * (rbase + u)];
        r1_p[u]  = dx4[2 * (rbase + u) + 1];
    }

    for (int tb = 0; tb < 32; tb += 2) {
        #pragma unroll
        for (int u = 0; u < 2; ++u) {
            const int tn = rbase + tb + u + 2;   // <= 257, zeroed slop
            float  own_n = dxs[tn][k];
            float  bb_n  = dxs[tn][j];
            float4 r0_n  = dx4[2 * tn];
            float4 r1_n  = dx4[2 * tn + 1];

            const float own = own_p[u];   // dx[k]
            const float bb  = bb_p[u];    // dx[j]
            const float4 r0 = r0_p[u];
            const float4 r1 = r1_p[u];
            const float rr[8] = { r0.x, r0.y, r0.z, r0.w, r1.x, r1.y, r1.z, r1.w };

            // level-4 coefficient for the block's two i's, read from the
            // (pre-update) t-state at compile-time slots 0/1.
            const float c4_0 = fmaf(own, fmaf(bb, fmaf(t1[0], (1.0f / 6.0f),
                                r0.x * (1.0f / 24.0f)), 0.5f * t2r[0]), t3r[0]);
            const float c4_1 = fmaf(own, fmaf(bb, fmaf(t1[1], (1.0f / 6.0f),
                                r0.y * (1.0f / 24.0f)), 0.5f * t2r[1]), t3r[1]);
            #pragma unroll
            for (int l = 0; l < 8; ++l) {
                s4v[0][l] = fmaf(c4_0, rr[l], s4v[0][l]);
                s4v[1][l] = fmaf(c4_1, rr[l], s4v[1][l]);
            }

            // full level1-3 update for the Chen table
            #pragma unroll
            for (int i = 0; i < 8; ++i) {
                const float a  = rr[i];
                const float c3 = fmaf(bb, fmaf(t1[i], 0.5f, a * (1.0f / 6.0f)), t2r[i]);
                t3r[i] = fmaf(c3, own, t3r[i]);
                t2r[i] = fmaf(fmaf(a, 0.5f, t1[i]), bb, t2r[i]);
                t1[i] += a;
            }

            own_p[u] = own_n; bb_p[u] = bb_n;
            r0_p[u] = r0_n;   r1_p[u] = r1_n;
        }
    }

    // chunk level1-3 -> table (permuted indices throughout)
    if (lane == 0) {
        #pragma unroll
        for (int i = 0; i < 8; ++i) sig3[w][i] = t1[i];
    }
    if (k == 0) {
        #pragma unroll
        for (int i = 0; i < 8; ++i) sig3[w][8 + i * 8 + j] = t2r[i];
    }
    #pragma unroll
    for (int i = 0; i < 8; ++i) sig3[w][72 + (i * 8 + j) * 8 + k] = t3r[i];
    __syncthreads();

    // ---------------- phase 3: Chen prefix + level-4 contribution ---------
    float p1[2] = {0.f, 0.f}, p2[2] = {0.f, 0.f}, p3[2] = {0.f, 0.f};

    auto combine = [&](int cc) {
        const float* __restrict__ lp = sig3[cc];
        const float s1j  = lp[j];
        const float s1k  = lp[k];
        const float s2jk = lp[8 + j * 8 + k];
        #pragma unroll
        for (int m = 0; m < 2; ++m) {
            const float s1i  = lp[m];                       // compile-time slot!
            const float s2ij = lp[8 + m * 8 + j];
            const float s3i  = lp[72 + (m * 8 + j) * 8 + k];
            const float np3 = p3[m] + s3i + p1[m] * s2jk + p2[m] * s1k;
            const float np2 = p2[m] + s2ij + p1[m] * s1j;
            p3[m] = np3; p2[m] = np2; p1[m] += s1i;
        }
    };

    for (int cc = 0; cc < w; ++cc) combine(cc);   // prefix before own chunk
    {   // s4v += P (x) own-chunk lower levels
        const float* __restrict__ lp = sig3[w];
        const float4 s1a = *reinterpret_cast<const float4*>(lp);
        const float4 s1b = *reinterpret_cast<const float4*>(lp + 4);
        const float4 s2a = *reinterpret_cast<const float4*>(lp + 8 + k * 8);
        const float4 s2b = *reinterpret_cast<const float4*>(lp + 8 + k * 8 + 4);
        const float4 s3a = *reinterpret_cast<const float4*>(lp + 72 + (j * 8 + k) * 8);
        const float4 s3b = *reinterpret_cast<const float4*>(lp + 72 + (j * 8 + k) * 8 + 4);
        const float s1r[8] = { s1a.x, s1a.y, s1a.z, s1a.w, s1b.x, s1b.y, s1b.z, s1b.w };
        const float s2r[8] = { s2a.x, s2a.y, s2a.z, s2a.w, s2b.x, s2b.y, s2b.z, s2b.w };
        const float s3r[8] = { s3a.x, s3a.y, s3a.z, s3a.w, s3b.x, s3b.y, s3b.z, s3b.w };
        #pragma unroll
        for (int m = 0; m < 2; ++m)
            #pragma unroll
            for (int l = 0; l < 8; ++l)
                s4v[m][l] = fmaf(p1[m], s3r[l],
                             fmaf(p2[m], s2r[l],
                              fmaf(p3[m], s1r[l], s4v[m][l])));
    }

    float* __restrict__ ob = out + (size_t)b * SIG_N;
    if (w == 7) {
        combine(7);   // full-path levels 1..3
        const int pj = PI(j);
        const int pk = PI(k);
        #pragma unroll
        for (int m = 0; m < 2; ++m) {
            const int i = i0 + m;                    // global row
            if (lane == 0) ob[i] = p1[m];
            if (k == 0)    ob[8 + i * 8 + pj] = p2[m];
            ob[72 + (i * 8 + pj) * 8 + pk] = p3[m];
        }
    }

    // ---------------- phase 4: per-wave s4 dump + ONE barrier -------------
    {
        float4* wp0 = reinterpret_cast<float4*>(&s4red[w][lane * 8]);
        wp0[0] = make_float4(s4v[0][0], s4v[0][1], s4v[0][2], s4v[0][3]);
        wp0[1] = make_float4(s4v[0][4], s4v[0][5], s4v[0][6], s4v[0][7]);
        float4* wp1 = reinterpret_cast<float4*>(&s4red[w][512 + lane * 8]);
        wp1[0] = make_float4(s4v[1][0], s4v[1][1], s4v[1][2], s4v[1][3]);
        wp1[1] = make_float4(s4v[1][4], s4v[1][5], s4v[1][6], s4v[1][7]);
    }
    __syncthreads();

    // ---------------- phase 5: tree-sum across waves + un-permuted store --
    {
        const int m  = tid >> 8;              // 0..1
        const int jk = (tid >> 2) & 63;       // permuted (j,k)
        const int l0 = (tid & 3) << 1;        // even pair base (permuted l)
        const int off = m * 512 + jk * 8 + l0;
        float2 v; v.x = 0.f; v.y = 0.f;
        #pragma unroll
        for (int ww = 0; ww < 8; ++ww) {      // ascending w: same sum order as R8
            const float2 t = *reinterpret_cast<const float2*>(&s4red[ww][off]);
            v.x += t.x; v.y += t.y;
        }
        const int jp = jk >> 3, kp = jk & 7;
        const int gj = PI(jp);
        const int gk = PI(kp);
        const int gl = PI(l0);                // even->even, pair preserved
        *reinterpret_cast<float2*>(ob + 584 + (i0 + m) * 512 + gj * 64 + gk * 8 + gl) = v;
    }
}

extern "C" void kernel_launch(void* const* d_in, const int* in_sizes, int n_in,
                              void* d_out, int out_size, void* d_ws, size_t ws_size,
                              hipStream_t stream)
{
    const float* inp = (const float*)d_in[0];
    const float* w1  = (const float*)d_in[1];
    const float* b1  = (const float*)d_in[2];
    const float* w2  = (const float*)d_in[3];
    const float* b2  = (const float*)d_in[4];
    const float* w3  = (const float*)d_in[5];
    const float* b3  = (const float*)d_in[6];
    float* out = (float*)d_out;

    sig_fused_kernel<<<256, 512, 0, stream>>>(inp, w1, b1, w2, b2, w3, b3, out);
}